// Round 9
// baseline (1589.516 us; speedup 1.0000x reference)
//
#include <hip/hip_runtime.h>

typedef __attribute__((ext_vector_type(8))) short bf16x8;
typedef __attribute__((ext_vector_type(8))) unsigned short u16x8;
typedef __attribute__((ext_vector_type(4))) float f32x4;
typedef unsigned short u16;
typedef unsigned int u32;

#define NN 50000
#define NE 800000

static __device__ __forceinline__ u16 f2bf(float f) {
  u32 u = __builtin_bit_cast(u32, f);
  u = (u + 0x7fffu + ((u >> 16) & 1u)) >> 16;
  return (u16)u;
}
static __device__ __forceinline__ float bf2f(u16 v) {
  u32 u = ((u32)v) << 16;
  return __builtin_bit_cast(float, u);
}
static __device__ __forceinline__ float relu_f(float v) { return v > 0.f ? v : 0.f; }

// ============================ CSR build ============================
__global__ void k_hist(const int* __restrict__ dstI, int* __restrict__ counts) {
  int e = blockIdx.x * 256 + threadIdx.x;
  if (e < NE) atomicAdd(&counts[dstI[e]], 1);
}

__global__ __launch_bounds__(1024) void k_scan(const int* __restrict__ counts, int* __restrict__ cur) {
  __shared__ int part[1024];
  int t = threadIdx.x;
  const int CH = (NN + 1023) / 1024;  // 49
  int base = t * CH;
  int s = 0;
  for (int i = 0; i < CH; ++i) {
    int idx = base + i;
    s += (idx < NN) ? counts[idx] : 0;
  }
  part[t] = s;
  __syncthreads();
  for (int off = 1; off < 1024; off <<= 1) {
    int v = (t >= off) ? part[t - off] : 0;
    __syncthreads();
    part[t] += v;
    __syncthreads();
  }
  int pre = (t == 0) ? 0 : part[t - 1];
  for (int i = 0; i < CH; ++i) {
    int idx = base + i;
    if (idx < NN) {
      cur[idx] = pre;
      pre += counts[idx];
    }
  }
}

__global__ void k_scatter(const int* __restrict__ dstI, int* __restrict__ cur, int* __restrict__ eperm) {
  int e = blockIdx.x * 256 + threadIdx.x;
  if (e < NE) {
    int d = dstI[e];
    int pos = atomicAdd(&cur[d], 1);
    eperm[pos] = e;
  }
}

// permute src/dst/edge_attr into dst-sorted order; edge_attr f32 -> bf16
__global__ void k_permute(const int* __restrict__ eperm,
                          const int* __restrict__ srcI, const int* __restrict__ dstI,
                          const float* __restrict__ ea,
                          int* __restrict__ srcS, int* __restrict__ dstS, u16* __restrict__ eaS) {
  int i = blockIdx.x * 256 + threadIdx.x;
  if (i >= NE) return;
  int e = eperm[i];
  srcS[i] = srcI[e];
  dstS[i] = dstI[e];
  const float4* ev = (const float4*)(ea + (size_t)e * 16);
  float4 a = ev[0], b = ev[1], c = ev[2], d = ev[3];
  u16x8 o0, o1;
  o0[0] = f2bf(a.x); o0[1] = f2bf(a.y); o0[2] = f2bf(a.z); o0[3] = f2bf(a.w);
  o0[4] = f2bf(b.x); o0[5] = f2bf(b.y); o0[6] = f2bf(b.z); o0[7] = f2bf(b.w);
  o1[0] = f2bf(c.x); o1[1] = f2bf(c.y); o1[2] = f2bf(c.z); o1[3] = f2bf(c.w);
  o1[4] = f2bf(d.x); o1[5] = f2bf(d.y); o1[6] = f2bf(d.z); o1[7] = f2bf(d.w);
  *(u16x8*)(eaS + (size_t)i * 16) = o0;
  *(u16x8*)(eaS + (size_t)i * 16 + 8) = o1;
}

// ============================ weight pack ============================
struct PackArgs {
  const float* src[24];
  u16* dst[24];
  int K[24];
  int Kpad[24];
};

__global__ void k_pack_all(PackArgs a) {
  int di = blockIdx.x / 144;
  int idx = (blockIdx.x - di * 144) * 256 + threadIdx.x;
  int Kpad = a.Kpad[di];
  if (idx >= 128 * Kpad) return;
  int c = idx / Kpad;
  int k = idx - c * Kpad;
  a.dst[di][idx] = (k < a.K[di]) ? f2bf(a.src[di][(size_t)k * 128 + c]) : (u16)0;
}

// ============================ embed: h = x @ embW + b ============================
__global__ __launch_bounds__(256, 2) void k_embed(
    const float* __restrict__ x, const u16* __restrict__ WT, const float* __restrict__ bias,
    float* __restrict__ h, u16* __restrict__ h_bf)
{
  __shared__ __align__(16) u16 A1[64][136];
  const int t = threadIdx.x;
  const int wv = t >> 6, ln = t & 63;
  const int l15 = ln & 15, hi = ln >> 4;
  const int col0 = wv * 32;

  bf16x8 wf[4][2];
#pragma unroll
  for (int kb = 0; kb < 4; ++kb)
#pragma unroll
    for (int nb = 0; nb < 2; ++nb)
      wf[kb][nb] = *(const bf16x8*)(WT + (col0 + nb * 16 + l15) * 128 + kb * 32 + hi * 8);
  float bv[2];
#pragma unroll
  for (int nb = 0; nb < 2; ++nb) bv[nb] = bias[col0 + nb * 16 + l15];

  const int r = t >> 2, p = t & 3;
  const int tile = blockIdx.x;
  {
    int node = tile * 64 + r;
    if (node < NN) {
      const float4* xv = (const float4*)(x + (size_t)node * 128) + p * 8;
#pragma unroll
      for (int i = 0; i < 4; ++i) {
        float4 v0 = xv[2 * i], v1 = xv[2 * i + 1];
        u16x8 o;
        o[0] = f2bf(v0.x); o[1] = f2bf(v0.y); o[2] = f2bf(v0.z); o[3] = f2bf(v0.w);
        o[4] = f2bf(v1.x); o[5] = f2bf(v1.y); o[6] = f2bf(v1.z); o[7] = f2bf(v1.w);
        *(u16x8*)(&A1[r][p * 32 + i * 8]) = o;
      }
    }
  }
  __syncthreads();

  f32x4 acc[4][2];
#pragma unroll
  for (int rb = 0; rb < 4; ++rb)
#pragma unroll
    for (int nb = 0; nb < 2; ++nb) acc[rb][nb] = (f32x4){0.f, 0.f, 0.f, 0.f};
#pragma unroll
  for (int kb = 0; kb < 4; ++kb) {
    bf16x8 af[4];
#pragma unroll
    for (int rb = 0; rb < 4; ++rb)
      af[rb] = *(const bf16x8*)(&A1[rb * 16 + l15][kb * 32 + hi * 8]);
#pragma unroll
    for (int rb = 0; rb < 4; ++rb)
#pragma unroll
      for (int nb = 0; nb < 2; ++nb)
        acc[rb][nb] = __builtin_amdgcn_mfma_f32_16x16x32_bf16(af[rb], wf[kb][nb], acc[rb][nb], 0, 0, 0);
  }
#pragma unroll
  for (int rb = 0; rb < 4; ++rb)
#pragma unroll
    for (int nb = 0; nb < 2; ++nb)
#pragma unroll
      for (int i = 0; i < 4; ++i) {
        int row = rb * 16 + hi * 4 + i;
        int node = tile * 64 + row;
        if (node < NN) {
          int col = col0 + nb * 16 + l15;
          float v = acc[rb][nb][i] + bv[nb];
          size_t ix = (size_t)node * 128 + col;
          h[ix] = v;
          h_bf[ix] = f2bf(v);
        }
      }
}

// ============================ Q precompute: Q = h_bf @ W1d (f32 out, no bias) =================
__global__ __launch_bounds__(256, 2) void k_qdst(
    const u16* __restrict__ h_bf, const u16* __restrict__ WT, float* __restrict__ Q)
{
  __shared__ __align__(16) u16 A1[64][136];
  const int t = threadIdx.x;
  const int wv = t >> 6, ln = t & 63;
  const int l15 = ln & 15, hi = ln >> 4;
  const int col0 = wv * 32;

  bf16x8 wf[4][2];
#pragma unroll
  for (int kb = 0; kb < 4; ++kb)
#pragma unroll
    for (int nb = 0; nb < 2; ++nb)
      wf[kb][nb] = *(const bf16x8*)(WT + (col0 + nb * 16 + l15) * 128 + kb * 32 + hi * 8);

  const int r = t >> 2, p = t & 3;
  const int tile = blockIdx.x;
  {
    int node = tile * 64 + r;
    if (node < NN) {
      const uint4* hv = (const uint4*)(h_bf + (size_t)node * 128) + p * 4;
      uint4* a0 = (uint4*)(&A1[r][0]) + p * 4;
#pragma unroll
      for (int i = 0; i < 4; ++i) a0[i] = hv[i];
    }
  }
  __syncthreads();

  f32x4 acc[4][2];
#pragma unroll
  for (int rb = 0; rb < 4; ++rb)
#pragma unroll
    for (int nb = 0; nb < 2; ++nb) acc[rb][nb] = (f32x4){0.f, 0.f, 0.f, 0.f};
#pragma unroll
  for (int kb = 0; kb < 4; ++kb) {
    bf16x8 af[4];
#pragma unroll
    for (int rb = 0; rb < 4; ++rb)
      af[rb] = *(const bf16x8*)(&A1[rb * 16 + l15][kb * 32 + hi * 8]);
#pragma unroll
    for (int rb = 0; rb < 4; ++rb)
#pragma unroll
      for (int nb = 0; nb < 2; ++nb)
        acc[rb][nb] = __builtin_amdgcn_mfma_f32_16x16x32_bf16(af[rb], wf[kb][nb], acc[rb][nb], 0, 0, 0);
  }
#pragma unroll
  for (int rb = 0; rb < 4; ++rb)
#pragma unroll
    for (int nb = 0; nb < 2; ++nb)
#pragma unroll
      for (int i = 0; i < 4; ++i) {
        int row = rb * 16 + hi * 4 + i;
        int node = tile * 64 + row;
        if (node < NN)
          Q[(size_t)node * 128 + col0 + nb * 16 + l15] = acc[rb][nb][i];
      }
}

// ============================ edge message kernel (dst-sorted, strided, Q-hoisted, 7 blk/CU) ==
// z = Q[dst] + [h_src|ea] @ W1s (K=160, continuation of Q's mfma chain)
// m = relu(relu(z) @ W2 + b2) rounded to bf16; agg[dst] += segmented f32 run-sums of bf16 m
__global__ __launch_bounds__(256, 7) void k_edge(
    const int* __restrict__ srcS, const int* __restrict__ dstS,
    const u16* __restrict__ h_bf, const u16* __restrict__ eaS,
    const float* __restrict__ Q,
    const u16* __restrict__ W1sT, const float* __restrict__ b1,
    const u16* __restrict__ W2T, const float* __restrict__ b2,
    float* __restrict__ agg)
{
  __shared__ __align__(16) u16 SH[64 * 168];  // A view stride 168; M view & m-bf16 view stride 136
  __shared__ int dstL[64];

  const int t = threadIdx.x;
  const int wv = t >> 6, ln = t & 63;
  const int l15 = ln & 15, hi = ln >> 4;
  const int col0 = wv * 32;

  bf16x8 w1f[5][2], w2f[4][2];
#pragma unroll
  for (int kb = 0; kb < 5; ++kb)
#pragma unroll
    for (int nb = 0; nb < 2; ++nb)
      w1f[kb][nb] = *(const bf16x8*)(W1sT + (col0 + nb * 16 + l15) * 160 + kb * 32 + hi * 8);
#pragma unroll
  for (int kb = 0; kb < 4; ++kb)
#pragma unroll
    for (int nb = 0; nb < 2; ++nb)
      w2f[kb][nb] = *(const bf16x8*)(W2T + (col0 + nb * 16 + l15) * 128 + kb * 32 + hi * 8);
  float b1v[2], b2v[2];
#pragma unroll
  for (int nb = 0; nb < 2; ++nb) {
    b1v[nb] = b1[col0 + nb * 16 + l15];
    b2v[nb] = b2[col0 + nb * 16 + l15];
  }

  const int r = t >> 2, p = t & 3;
  const int NT = NE / 64;

  int tile = blockIdx.x;
  int s_nx = srcS[tile * 64 + r];
  int d_nx = dstS[tile * 64 + r];

  for (; tile < NT; tile += gridDim.x) {
    f32x4 acc1[4][2];
    // ---- gather: A row = [h[src](128) | ea(16) | 0(16)] ; acc1 <- Q[dst] ----
    {
      int e = tile * 64 + r;
      int s = s_nx;
      if (p == 0) dstL[r] = d_nx;
      const uint4* hs = (const uint4*)(h_bf + (size_t)s * 128) + p * 4;
      uint4* a1 = (uint4*)(&SH[r * 168]) + p * 4;
#pragma unroll
      for (int i = 0; i < 4; ++i) a1[i] = hs[i];
      if (p == 1) {
        const uint4* ea = (const uint4*)(eaS + (size_t)e * 16);
        uint4* aE = (uint4*)(&SH[r * 168 + 128]);
        aE[0] = ea[0]; aE[1] = ea[1];
      } else if (p == 2) {
        uint4 z = make_uint4(0, 0, 0, 0);
        uint4* aZ = (uint4*)(&SH[r * 168 + 144]);
        aZ[0] = z; aZ[1] = z;
      }
      // Q[dst] loads into acc1 (per-lane; dst runs make these L1/L2-hot)
      int e0 = tile * 64;
#pragma unroll
      for (int rb = 0; rb < 4; ++rb) {
#pragma unroll
        for (int i = 0; i < 4; ++i) {
          int dr = dstS[e0 + rb * 16 + hi * 4 + i];
          const float* qp = Q + (size_t)dr * 128 + col0 + l15;
          acc1[rb][0][i] = qp[0];
          acc1[rb][1][i] = qp[16];
        }
      }
      // prefetch next tile's indices (lands during compute)
      int tn = tile + gridDim.x;
      if (tn < NT) {
        int en = tn * 64 + r;
        s_nx = srcS[en];
        d_nx = dstS[en];
      }
    }
    __syncthreads();

    // ---- stage 1: acc1 += [64,160] @ [160,128] (continuation of Q chain) ----
#pragma unroll
    for (int kb = 0; kb < 5; ++kb) {
      bf16x8 af[4];
#pragma unroll
      for (int rb = 0; rb < 4; ++rb)
        af[rb] = *(const bf16x8*)(&SH[(rb * 16 + l15) * 168 + kb * 32 + hi * 8]);
#pragma unroll
      for (int rb = 0; rb < 4; ++rb)
#pragma unroll
        for (int nb = 0; nb < 2; ++nb)
          acc1[rb][nb] = __builtin_amdgcn_mfma_f32_16x16x32_bf16(af[rb], w1f[kb][nb], acc1[rb][nb], 0, 0, 0);
    }
    __syncthreads();  // A reads done before M overwrites union buffer

    // ---- write M (relu, bf16), stride 136 ----
#pragma unroll
    for (int rb = 0; rb < 4; ++rb)
#pragma unroll
      for (int nb = 0; nb < 2; ++nb)
#pragma unroll
        for (int i = 0; i < 4; ++i) {
          float v = acc1[rb][nb][i] + b1v[nb];
          SH[(rb * 16 + hi * 4 + i) * 136 + col0 + nb * 16 + l15] = f2bf(relu_f(v));
        }
    __syncthreads();

    // ---- stage 2: [64,128] @ [128,128] ----
    f32x4 acc2[4][2];
#pragma unroll
    for (int rb = 0; rb < 4; ++rb)
#pragma unroll
      for (int nb = 0; nb < 2; ++nb) acc2[rb][nb] = (f32x4){0.f, 0.f, 0.f, 0.f};
#pragma unroll
    for (int kb = 0; kb < 4; ++kb) {
      bf16x8 af[4];
#pragma unroll
      for (int rb = 0; rb < 4; ++rb)
        af[rb] = *(const bf16x8*)(&SH[(rb * 16 + l15) * 136 + kb * 32 + hi * 8]);
#pragma unroll
      for (int rb = 0; rb < 4; ++rb)
#pragma unroll
        for (int nb = 0; nb < 2; ++nb)
          acc2[rb][nb] = __builtin_amdgcn_mfma_f32_16x16x32_bf16(af[rb], w2f[kb][nb], acc2[rb][nb], 0, 0, 0);
    }
    __syncthreads();  // M reads done before m-bf16 overwrites the region

    // ---- write m (relu, bf16) into the M region, stride 136 ----
#pragma unroll
    for (int rb = 0; rb < 4; ++rb)
#pragma unroll
      for (int nb = 0; nb < 2; ++nb)
#pragma unroll
        for (int i = 0; i < 4; ++i) {
          float v = relu_f(acc2[rb][nb][i] + b2v[nb]);
          SH[(rb * 16 + hi * 4 + i) * 136 + col0 + nb * 16 + l15] = f2bf(v);
        }
    __syncthreads();

    // ---- segmented scan over sorted dst runs (bf16 m, f32 run sums); same structure ----
    {
      int c = t & 127, hh = t >> 7;
      int r0 = hh * 32;
      int d0 = dstL[r0];
      float run = bf2f(SH[r0 * 136 + c]);
#pragma unroll 4
      for (int rr = r0 + 1; rr < r0 + 32; ++rr) {
        int d = dstL[rr];              // wave-uniform
        float v = bf2f(SH[rr * 136 + c]);
        if (d != d0) {                 // wave-uniform branch
          atomicAdd(&agg[(size_t)d0 * 128 + c], run);
          d0 = d; run = v;
        } else {
          run += v;
        }
      }
      atomicAdd(&agg[(size_t)d0 * 128 + c], run);
    }
    __syncthreads();  // scan reads done before next iteration's LDS writes
  }
}

// ============================ node update ============================
// u = relu(cat(h,agg) @ W1 + b1) @ W2 + b2;  h += u  (h_bf mirrored); agg f32
__global__ __launch_bounds__(256, 4) void k_node_update(
    const float* __restrict__ aggIn,
    const u16* __restrict__ W1T, const float* __restrict__ b1,
    const u16* __restrict__ W2T, const float* __restrict__ b2,
    float* __restrict__ h, u16* __restrict__ h_bf)
{
  __shared__ __align__(16) u16 SH[64 * 264];
  const int t = threadIdx.x;
  const int wv = t >> 6, ln = t & 63;
  const int l15 = ln & 15, hi = ln >> 4;
  const int col0 = wv * 32;

  bf16x8 w1f[8][2], w2f[4][2];
#pragma unroll
  for (int kb = 0; kb < 8; ++kb)
#pragma unroll
    for (int nb = 0; nb < 2; ++nb)
      w1f[kb][nb] = *(const bf16x8*)(W1T + (col0 + nb * 16 + l15) * 256 + kb * 32 + hi * 8);
#pragma unroll
  for (int kb = 0; kb < 4; ++kb)
#pragma unroll
    for (int nb = 0; nb < 2; ++nb)
      w2f[kb][nb] = *(const bf16x8*)(W2T + (col0 + nb * 16 + l15) * 128 + kb * 32 + hi * 8);
  float b1v[2], b2v[2];
#pragma unroll
  for (int nb = 0; nb < 2; ++nb) {
    b1v[nb] = b1[col0 + nb * 16 + l15];
    b2v[nb] = b2[col0 + nb * 16 + l15];
  }

  const int r = t >> 2, p = t & 3;
  const int tile = blockIdx.x;
  {
    int node = tile * 64 + r;
    if (node < NN) {
      const uint4* hv = (const uint4*)(h_bf + (size_t)node * 128) + p * 4;
      uint4* a0 = (uint4*)(&SH[r * 264]) + p * 4;
#pragma unroll
      for (int i = 0; i < 4; ++i) a0[i] = hv[i];
      const float4* ag = (const float4*)(aggIn + (size_t)node * 128) + p * 8;
#pragma unroll
      for (int i = 0; i < 4; ++i) {
        float4 v0 = ag[2 * i], v1 = ag[2 * i + 1];
        u16x8 o;
        o[0] = f2bf(v0.x); o[1] = f2bf(v0.y); o[2] = f2bf(v0.z); o[3] = f2bf(v0.w);
        o[4] = f2bf(v1.x); o[5] = f2bf(v1.y); o[6] = f2bf(v1.z); o[7] = f2bf(v1.w);
        *(u16x8*)(&SH[r * 264 + 128 + p * 32 + i * 8]) = o;
      }
    }
  }
  __syncthreads();

  f32x4 acc1[4][2];
#pragma unroll
  for (int rb = 0; rb < 4; ++rb)
#pragma unroll
    for (int nb = 0; nb < 2; ++nb) acc1[rb][nb] = (f32x4){0.f, 0.f, 0.f, 0.f};
#pragma unroll
  for (int kb = 0; kb < 8; ++kb) {
    bf16x8 af[4];
#pragma unroll
    for (int rb = 0; rb < 4; ++rb)
      af[rb] = *(const bf16x8*)(&SH[(rb * 16 + l15) * 264 + kb * 32 + hi * 8]);
#pragma unroll
    for (int rb = 0; rb < 4; ++rb)
#pragma unroll
      for (int nb = 0; nb < 2; ++nb)
        acc1[rb][nb] = __builtin_amdgcn_mfma_f32_16x16x32_bf16(af[rb], w1f[kb][nb], acc1[rb][nb], 0, 0, 0);
  }
  __syncthreads();

#pragma unroll
  for (int rb = 0; rb < 4; ++rb)
#pragma unroll
    for (int nb = 0; nb < 2; ++nb)
#pragma unroll
      for (int i = 0; i < 4; ++i) {
        float v = acc1[rb][nb][i] + b1v[nb];
        SH[(rb * 16 + hi * 4 + i) * 136 + col0 + nb * 16 + l15] = f2bf(relu_f(v));
      }
  __syncthreads();

  f32x4 acc2[4][2];
#pragma unroll
  for (int rb = 0; rb < 4; ++rb)
#pragma unroll
    for (int nb = 0; nb < 2; ++nb) acc2[rb][nb] = (f32x4){0.f, 0.f, 0.f, 0.f};
#pragma unroll
  for (int kb = 0; kb < 4; ++kb) {
    bf16x8 af[4];
#pragma unroll
    for (int rb = 0; rb < 4; ++rb)
      af[rb] = *(const bf16x8*)(&SH[(rb * 16 + l15) * 136 + kb * 32 + hi * 8]);
#pragma unroll
    for (int rb = 0; rb < 4; ++rb)
#pragma unroll
      for (int nb = 0; nb < 2; ++nb)
        acc2[rb][nb] = __builtin_amdgcn_mfma_f32_16x16x32_bf16(af[rb], w2f[kb][nb], acc2[rb][nb], 0, 0, 0);
  }
#pragma unroll
  for (int rb = 0; rb < 4; ++rb)
#pragma unroll
    for (int nb = 0; nb < 2; ++nb)
#pragma unroll
      for (int i = 0; i < 4; ++i) {
        int row = rb * 16 + hi * 4 + i;
        int node = tile * 64 + row;
        if (node < NN) {
          int col = col0 + nb * 16 + l15;
          float v = acc2[rb][nb][i] + b2v[nb];
          size_t ix = (size_t)node * 128 + col;
          float nh = h[ix] + v;
          h[ix] = nh;
          h_bf[ix] = f2bf(nh);
        }
      }
}

// ============================ pre-pool MLP + global add pool (segmented, batch sorted) =========
__global__ __launch_bounds__(256, 4) void k_prepool(
    const u16* __restrict__ h_bf, const int* __restrict__ batch,
    const u16* __restrict__ W1T, const float* __restrict__ b1,
    const u16* __restrict__ W2T, const float* __restrict__ b2,
    float* __restrict__ g)
{
  __shared__ __align__(16) u16 SH[64 * 272];  // A [64][136] @0; M [64][136] @64*136; f32 view [64][132]
  __shared__ int bL[64];
  float* SHf = (float*)SH;
  const int t = threadIdx.x;
  const int wv = t >> 6, ln = t & 63;
  const int l15 = ln & 15, hi = ln >> 4;
  const int col0 = wv * 32;

  bf16x8 w1f[4][2], w2f[4][2];
#pragma unroll
  for (int kb = 0; kb < 4; ++kb)
#pragma unroll
    for (int nb = 0; nb < 2; ++nb) {
      w1f[kb][nb] = *(const bf16x8*)(W1T + (col0 + nb * 16 + l15) * 128 + kb * 32 + hi * 8);
      w2f[kb][nb] = *(const bf16x8*)(W2T + (col0 + nb * 16 + l15) * 128 + kb * 32 + hi * 8);
    }
  float b1v[2], b2v[2];
#pragma unroll
  for (int nb = 0; nb < 2; ++nb) {
    b1v[nb] = b1[col0 + nb * 16 + l15];
    b2v[nb] = b2[col0 + nb * 16 + l15];
  }

  const int r = t >> 2, p = t & 3;
  const int tile = blockIdx.x;
  {
    int node = tile * 64 + r;
    int nclamp = node < NN ? node : NN - 1;
    if (p == 0) bL[r] = batch[nclamp];
    if (node < NN) {
      const uint4* hv = (const uint4*)(h_bf + (size_t)node * 128) + p * 4;
      uint4* a0 = (uint4*)(&SH[r * 136]) + p * 4;
#pragma unroll
      for (int i = 0; i < 4; ++i) a0[i] = hv[i];
    }
  }
  __syncthreads();

  f32x4 acc1[4][2];
#pragma unroll
  for (int rb = 0; rb < 4; ++rb)
#pragma unroll
    for (int nb = 0; nb < 2; ++nb) acc1[rb][nb] = (f32x4){0.f, 0.f, 0.f, 0.f};
#pragma unroll
  for (int kb = 0; kb < 4; ++kb) {
    bf16x8 af[4];
#pragma unroll
    for (int rb = 0; rb < 4; ++rb)
      af[rb] = *(const bf16x8*)(&SH[(rb * 16 + l15) * 136 + kb * 32 + hi * 8]);
#pragma unroll
    for (int rb = 0; rb < 4; ++rb)
#pragma unroll
      for (int nb = 0; nb < 2; ++nb)
        acc1[rb][nb] = __builtin_amdgcn_mfma_f32_16x16x32_bf16(af[rb], w1f[kb][nb], acc1[rb][nb], 0, 0, 0);
  }
  // M region disjoint from A region: no barrier needed before write
#pragma unroll
  for (int rb = 0; rb < 4; ++rb)
#pragma unroll
    for (int nb = 0; nb < 2; ++nb)
#pragma unroll
      for (int i = 0; i < 4; ++i) {
        float v = acc1[rb][nb][i] + b1v[nb];
        SH[64 * 136 + (rb * 16 + hi * 4 + i) * 136 + col0 + nb * 16 + l15] = f2bf(relu_f(v));
      }
  __syncthreads();

  f32x4 acc2[4][2];
#pragma unroll
  for (int rb = 0; rb < 4; ++rb)
#pragma unroll
    for (int nb = 0; nb < 2; ++nb) acc2[rb][nb] = (f32x4){0.f, 0.f, 0.f, 0.f};
#pragma unroll
  for (int kb = 0; kb < 4; ++kb) {
    bf16x8 af[4];
#pragma unroll
    for (int rb = 0; rb < 4; ++rb)
      af[rb] = *(const bf16x8*)(&SH[64 * 136 + (rb * 16 + l15) * 136 + kb * 32 + hi * 8]);
#pragma unroll
    for (int rb = 0; rb < 4; ++rb)
#pragma unroll
      for (int nb = 0; nb < 2; ++nb)
        acc2[rb][nb] = __builtin_amdgcn_mfma_f32_16x16x32_bf16(af[rb], w2f[kb][nb], acc2[rb][nb], 0, 0, 0);
  }
  __syncthreads();  // all A/M reads done before f32 view overwrites

  // write p (f32, zero for invalid rows) to SHf [64][132]
#pragma unroll
  for (int rb = 0; rb < 4; ++rb)
#pragma unroll
    for (int nb = 0; nb < 2; ++nb)
#pragma unroll
      for (int i = 0; i < 4; ++i) {
        int row = rb * 16 + hi * 4 + i;
        int node = tile * 64 + row;
        float v = acc2[rb][nb][i] + b2v[nb];
        SHf[row * 132 + col0 + nb * 16 + l15] = (node < NN) ? v : 0.f;
      }
  __syncthreads();

  // segmented scan over sorted batch ids; one atomic per (segment, col)
  {
    int c = t & 127, hh = t >> 7;
    int r0 = hh * 32;
    int b0 = bL[r0];
    float run = SHf[r0 * 132 + c];
#pragma unroll 4
    for (int rr = r0 + 1; rr < r0 + 32; ++rr) {
      int b = bL[rr];                // wave-uniform
      float v = SHf[rr * 132 + c];
      if (b != b0) {                 // wave-uniform branch
        atomicAdd(&g[(size_t)b0 * 128 + c], run);
        b0 = b; run = v;
      } else {
        run += v;
      }
    }
    atomicAdd(&g[(size_t)b0 * 128 + c], run);
  }
}

// ============================ post-pool MLP (tiny, fp32) ============================
__global__ void k_postpool(const float* __restrict__ g,
                           const float* __restrict__ W1, const float* __restrict__ b1,
                           const float* __restrict__ W2, const float* __restrict__ b2,
                           float* __restrict__ out)
{
  __shared__ float gl[16][128];
  __shared__ float t1[16][129];
  int t = threadIdx.x;
  for (int i = t; i < 16 * 128; i += 256) gl[i >> 7][i & 127] = g[i];
  __syncthreads();
  for (int o = t; o < 16 * 128; o += 256) {
    int r = o >> 7, c = o & 127;
    float s = b1[c];
    for (int k = 0; k < 128; ++k) s += gl[r][k] * W1[k * 128 + c];
    t1[r][c] = relu_f(s);
  }
  __syncthreads();
  for (int o = t; o < 16 * 128; o += 256) {
    int r = o >> 7, c = o & 127;
    float s = b2[c];
    for (int k = 0; k < 128; ++k) s += t1[r][k] * W2[k * 128 + c];
    out[o] = s;
  }
}

// ============================ host ============================
extern "C" void kernel_launch(void* const* d_in, const int* in_sizes, int n_in,
                              void* d_out, int out_size, void* d_ws, size_t ws_size,
                              hipStream_t stream) {
  (void)in_sizes; (void)n_in; (void)out_size; (void)ws_size;
  const float* x      = (const float*)d_in[0];
  const int*   ei     = (const int*)d_in[1];
  const float* ea     = (const float*)d_in[2];
  const int*   batch  = (const int*)d_in[3];
  const float* embW   = (const float*)d_in[4];
  const float* embb   = (const float*)d_in[5];
  const float* msgW1  = (const float*)d_in[6];
  const float* msgb1  = (const float*)d_in[7];
  const float* msgW2  = (const float*)d_in[8];
  const float* msgb2  = (const float*)d_in[9];
  const float* updW1  = (const float*)d_in[10];
  const float* updb1  = (const float*)d_in[11];
  const float* updW2  = (const float*)d_in[12];
  const float* updb2  = (const float*)d_in[13];
  const float* preW1  = (const float*)d_in[14];
  const float* preb1  = (const float*)d_in[15];
  const float* preW2  = (const float*)d_in[16];
  const float* preb2  = (const float*)d_in[17];
  const float* postW1 = (const float*)d_in[18];
  const float* postb1 = (const float*)d_in[19];
  const float* postW2 = (const float*)d_in[20];
  const float* postb2 = (const float*)d_in[21];

  const int* srcI = ei;
  const int* dstI = ei + NE;

  char* ws = (char*)d_ws;
  size_t off = 0;
  auto alloc = [&](size_t bytes) -> void* {
    void* pp = ws + off;
    off += (bytes + 255) & ~(size_t)255;
    return pp;
  };
  float* h      = (float*)alloc((size_t)NN * 128 * 4);
  float* agg    = (float*)alloc((size_t)NN * 128 * 4);
  float* Q      = (float*)alloc((size_t)NN * 128 * 4);
  float* g      = (float*)alloc(16 * 128 * 4);
  u16*   h_bf   = (u16*)alloc((size_t)NN * 128 * 2);
  u16*   eaS    = (u16*)alloc((size_t)NE * 16 * 2);
  int*   counts = (int*)alloc((size_t)NN * 4);
  int*   cur    = (int*)alloc((size_t)NN * 4);
  int*   eperm  = (int*)alloc((size_t)NE * 4);
  int*   srcS   = (int*)alloc((size_t)NE * 4);
  int*   dstS   = (int*)alloc((size_t)NE * 4);
  u16*   embWT  = (u16*)alloc(128 * 128 * 2);
  u16*   msgW1dT = (u16*)alloc(4 * 128 * 128 * 2);
  u16*   msgW1sT = (u16*)alloc(4 * 128 * 160 * 2);
  u16*   msgW2T = (u16*)alloc(4 * 128 * 128 * 2);
  u16*   updW1T = (u16*)alloc(4 * 128 * 256 * 2);
  u16*   updW2T = (u16*)alloc(4 * 128 * 128 * 2);
  u16*   preW1T = (u16*)alloc(128 * 128 * 2);
  u16*   preW2T = (u16*)alloc(128 * 128 * 2);

  // ---- CSR build (dst-sorted edge order) ----
  hipMemsetAsync(counts, 0, (size_t)NN * 4, stream);
  const int eBlocks = (NE + 255) / 256;
  k_hist<<<eBlocks, 256, 0, stream>>>(dstI, counts);
  k_scan<<<1, 1024, 0, stream>>>(counts, cur);
  k_scatter<<<eBlocks, 256, 0, stream>>>(dstI, cur, eperm);
  k_permute<<<eBlocks, 256, 0, stream>>>(eperm, srcI, dstI, ea, srcS, dstS, eaS);

  // ---- weight pack ----
  {
    PackArgs pa;
    int di = 0;
    auto add = [&](const float* s, u16* dp, int K, int Kpad) {
      pa.src[di] = s; pa.dst[di] = dp; pa.K[di] = K; pa.Kpad[di] = Kpad; ++di;
    };
    add(embW, embWT, 128, 128);
    for (int l = 0; l < 4; ++l) add(msgW1 + (size_t)l * 272 * 128, msgW1dT + (size_t)l * 128 * 128, 128, 128);
    for (int l = 0; l < 4; ++l) add(msgW1 + (size_t)l * 272 * 128 + 128 * 128, msgW1sT + (size_t)l * 128 * 160, 144, 160);
    for (int l = 0; l < 4; ++l) add(msgW2 + (size_t)l * 128 * 128, msgW2T + (size_t)l * 128 * 128, 128, 128);
    for (int l = 0; l < 4; ++l) add(updW1 + (size_t)l * 256 * 128, updW1T + (size_t)l * 128 * 256, 256, 256);
    for (int l = 0; l < 4; ++l) add(updW2 + (size_t)l * 128 * 128, updW2T + (size_t)l * 128 * 128, 128, 128);
    add(preW1, preW1T, 128, 128);
    add(preW2, preW2T, 128, 128);
    k_pack_all<<<23 * 144, 256, 0, stream>>>(pa);
  }

  const int nodeTiles = (NN + 63) / 64;
  k_embed<<<nodeTiles, 256, 0, stream>>>(x, embWT, embb, h, h_bf);

  for (int l = 0; l < 4; ++l) {
    k_qdst<<<nodeTiles, 256, 0, stream>>>(h_bf, msgW1dT + (size_t)l * 128 * 128, Q);
    hipMemsetAsync(agg, 0, (size_t)NN * 128 * 4, stream);
    k_edge<<<1792, 256, 0, stream>>>(srcS, dstS, h_bf, eaS, Q,
                                     msgW1sT + (size_t)l * 128 * 160, msgb1 + l * 128,
                                     msgW2T + (size_t)l * 128 * 128, msgb2 + l * 128, agg);
    k_node_update<<<nodeTiles, 256, 0, stream>>>(agg,
                                    updW1T + (size_t)l * 128 * 256, updb1 + l * 128,
                                    updW2T + (size_t)l * 128 * 128, updb2 + l * 128,
                                    h, h_bf);
  }

  hipMemsetAsync(g, 0, 16 * 128 * 4, stream);
  k_prepool<<<nodeTiles, 256, 0, stream>>>(h_bf, batch, preW1T, preb1, preW2T, preb2, g);
  k_postpool<<<1, 256, 0, stream>>>(g, postW1, postb1, postW2, postb2, (float*)d_out);
}

// Round 10
// 1124.562 us; speedup vs baseline: 1.4135x; 1.4135x over previous
//
#include <hip/hip_runtime.h>

typedef __attribute__((ext_vector_type(8))) short bf16x8;
typedef __attribute__((ext_vector_type(8))) unsigned short u16x8;
typedef __attribute__((ext_vector_type(4))) float f32x4;
typedef unsigned short u16;
typedef unsigned int u32;

#define NN 50000
#define NE 800000

static __device__ __forceinline__ u16 f2bf(float f) {
  u32 u = __builtin_bit_cast(u32, f);
  u = (u + 0x7fffu + ((u >> 16) & 1u)) >> 16;
  return (u16)u;
}
static __device__ __forceinline__ float relu_f(float v) { return v > 0.f ? v : 0.f; }

// ============================ CSR build ============================
__global__ void k_hist(const int* __restrict__ dstI, int* __restrict__ counts) {
  int e = blockIdx.x * 256 + threadIdx.x;
  if (e < NE) atomicAdd(&counts[dstI[e]], 1);
}

__global__ __launch_bounds__(1024) void k_scan(const int* __restrict__ counts, int* __restrict__ cur) {
  __shared__ int part[1024];
  int t = threadIdx.x;
  const int CH = (NN + 1023) / 1024;  // 49
  int base = t * CH;
  int s = 0;
  for (int i = 0; i < CH; ++i) {
    int idx = base + i;
    s += (idx < NN) ? counts[idx] : 0;
  }
  part[t] = s;
  __syncthreads();
  for (int off = 1; off < 1024; off <<= 1) {
    int v = (t >= off) ? part[t - off] : 0;
    __syncthreads();
    part[t] += v;
    __syncthreads();
  }
  int pre = (t == 0) ? 0 : part[t - 1];
  for (int i = 0; i < CH; ++i) {
    int idx = base + i;
    if (idx < NN) {
      cur[idx] = pre;
      pre += counts[idx];
    }
  }
}

__global__ void k_scatter(const int* __restrict__ dstI, int* __restrict__ cur, int* __restrict__ eperm) {
  int e = blockIdx.x * 256 + threadIdx.x;
  if (e < NE) {
    int d = dstI[e];
    int pos = atomicAdd(&cur[d], 1);
    eperm[pos] = e;
  }
}

// permute src/dst/edge_attr into dst-sorted order; edge_attr f32 -> bf16
__global__ void k_permute(const int* __restrict__ eperm,
                          const int* __restrict__ srcI, const int* __restrict__ dstI,
                          const float* __restrict__ ea,
                          int* __restrict__ srcS, int* __restrict__ dstS, u16* __restrict__ eaS) {
  int i = blockIdx.x * 256 + threadIdx.x;
  if (i >= NE) return;
  int e = eperm[i];
  srcS[i] = srcI[e];
  dstS[i] = dstI[e];
  const float4* ev = (const float4*)(ea + (size_t)e * 16);
  float4 a = ev[0], b = ev[1], c = ev[2], d = ev[3];
  u16x8 o0, o1;
  o0[0] = f2bf(a.x); o0[1] = f2bf(a.y); o0[2] = f2bf(a.z); o0[3] = f2bf(a.w);
  o0[4] = f2bf(b.x); o0[5] = f2bf(b.y); o0[6] = f2bf(b.z); o0[7] = f2bf(b.w);
  o1[0] = f2bf(c.x); o1[1] = f2bf(c.y); o1[2] = f2bf(c.z); o1[3] = f2bf(c.w);
  o1[4] = f2bf(d.x); o1[5] = f2bf(d.y); o1[6] = f2bf(d.z); o1[7] = f2bf(d.w);
  *(u16x8*)(eaS + (size_t)i * 16) = o0;
  *(u16x8*)(eaS + (size_t)i * 16 + 8) = o1;
}

// ============================ weight pack ============================
struct PackArgs {
  const float* src[24];
  u16* dst[24];
  int K[24];
  int Kpad[24];
};

__global__ void k_pack_all(PackArgs a) {
  int di = blockIdx.x / 144;
  int idx = (blockIdx.x - di * 144) * 256 + threadIdx.x;
  int Kpad = a.Kpad[di];
  if (idx >= 128 * Kpad) return;
  int c = idx / Kpad;
  int k = idx - c * Kpad;
  a.dst[di][idx] = (k < a.K[di]) ? f2bf(a.src[di][(size_t)k * 128 + c]) : (u16)0;
}

// ============================ embed: h = x @ embW + b; Q = h_bf @ W1d0 (fused) ================
__global__ __launch_bounds__(256, 2) void k_embed(
    const float* __restrict__ x, const u16* __restrict__ WT, const float* __restrict__ bias,
    const u16* __restrict__ W1dT, float* __restrict__ Q,
    float* __restrict__ h, u16* __restrict__ h_bf)
{
  __shared__ __align__(16) u16 A1[64][136];
  const int t = threadIdx.x;
  const int wv = t >> 6, ln = t & 63;
  const int l15 = ln & 15, hi = ln >> 4;
  const int col0 = wv * 32;

  bf16x8 wf[4][2];
#pragma unroll
  for (int kb = 0; kb < 4; ++kb)
#pragma unroll
    for (int nb = 0; nb < 2; ++nb)
      wf[kb][nb] = *(const bf16x8*)(WT + (col0 + nb * 16 + l15) * 128 + kb * 32 + hi * 8);
  float bv[2];
#pragma unroll
  for (int nb = 0; nb < 2; ++nb) bv[nb] = bias[col0 + nb * 16 + l15];

  const int r = t >> 2, p = t & 3;
  const int tile = blockIdx.x;
  {
    int node = tile * 64 + r;
    if (node < NN) {
      const float4* xv = (const float4*)(x + (size_t)node * 128) + p * 8;
#pragma unroll
      for (int i = 0; i < 4; ++i) {
        float4 v0 = xv[2 * i], v1 = xv[2 * i + 1];
        u16x8 o;
        o[0] = f2bf(v0.x); o[1] = f2bf(v0.y); o[2] = f2bf(v0.z); o[3] = f2bf(v0.w);
        o[4] = f2bf(v1.x); o[5] = f2bf(v1.y); o[6] = f2bf(v1.z); o[7] = f2bf(v1.w);
        *(u16x8*)(&A1[r][p * 32 + i * 8]) = o;
      }
    }
  }
  __syncthreads();

  f32x4 acc[4][2];
#pragma unroll
  for (int rb = 0; rb < 4; ++rb)
#pragma unroll
    for (int nb = 0; nb < 2; ++nb) acc[rb][nb] = (f32x4){0.f, 0.f, 0.f, 0.f};
#pragma unroll
  for (int kb = 0; kb < 4; ++kb) {
    bf16x8 af[4];
#pragma unroll
    for (int rb = 0; rb < 4; ++rb)
      af[rb] = *(const bf16x8*)(&A1[rb * 16 + l15][kb * 32 + hi * 8]);
#pragma unroll
    for (int rb = 0; rb < 4; ++rb)
#pragma unroll
      for (int nb = 0; nb < 2; ++nb)
        acc[rb][nb] = __builtin_amdgcn_mfma_f32_16x16x32_bf16(af[rb], wf[kb][nb], acc[rb][nb], 0, 0, 0);
  }
  __syncthreads();  // all A1 reads done before the bf16-h image overwrites it

#pragma unroll
  for (int rb = 0; rb < 4; ++rb)
#pragma unroll
    for (int nb = 0; nb < 2; ++nb)
#pragma unroll
      for (int i = 0; i < 4; ++i) {
        int row = rb * 16 + hi * 4 + i;
        int node = tile * 64 + row;
        if (node < NN) {
          int col = col0 + nb * 16 + l15;
          float v = acc[rb][nb][i] + bv[nb];
          size_t ix = (size_t)node * 128 + col;
          u16 hb = f2bf(v);
          h[ix] = v;
          h_bf[ix] = hb;
          A1[row][col] = hb;   // stage new h (bf16) for the fused Q chain
        }
      }
  __syncthreads();

  // ---- fused Q = h_bf @ W1d (layer 0), bit-identical to the standalone chain ----
  bf16x8 wq[4][2];
#pragma unroll
  for (int kb = 0; kb < 4; ++kb)
#pragma unroll
    for (int nb = 0; nb < 2; ++nb)
      wq[kb][nb] = *(const bf16x8*)(W1dT + (col0 + nb * 16 + l15) * 128 + kb * 32 + hi * 8);
  f32x4 aq[4][2];
#pragma unroll
  for (int rb = 0; rb < 4; ++rb)
#pragma unroll
    for (int nb = 0; nb < 2; ++nb) aq[rb][nb] = (f32x4){0.f, 0.f, 0.f, 0.f};
#pragma unroll
  for (int kb = 0; kb < 4; ++kb) {
    bf16x8 af[4];
#pragma unroll
    for (int rb = 0; rb < 4; ++rb)
      af[rb] = *(const bf16x8*)(&A1[rb * 16 + l15][kb * 32 + hi * 8]);
#pragma unroll
    for (int rb = 0; rb < 4; ++rb)
#pragma unroll
      for (int nb = 0; nb < 2; ++nb)
        aq[rb][nb] = __builtin_amdgcn_mfma_f32_16x16x32_bf16(af[rb], wq[kb][nb], aq[rb][nb], 0, 0, 0);
  }
#pragma unroll
  for (int rb = 0; rb < 4; ++rb)
#pragma unroll
    for (int nb = 0; nb < 2; ++nb)
#pragma unroll
      for (int i = 0; i < 4; ++i) {
        int row = rb * 16 + hi * 4 + i;
        int node = tile * 64 + row;
        if (node < NN)
          Q[(size_t)node * 128 + col0 + nb * 16 + l15] = aq[rb][nb][i];
      }
}

// ============================ edge message kernel (EXACT r8 config) ==========================
// z = Q[dst] + [h_src|ea] @ W1s (K=160, continuation of Q's mfma chain)
// m = relu(relu(z) @ W2 + b2);  agg[dst] += m via segmented scan (f32 view)
__global__ __launch_bounds__(256, 4) void k_edge(
    const int* __restrict__ srcS, const int* __restrict__ dstS,
    const u16* __restrict__ h_bf, const u16* __restrict__ eaS,
    const float* __restrict__ Q,
    const u16* __restrict__ W1sT, const float* __restrict__ b1,
    const u16* __restrict__ W2T, const float* __restrict__ b2,
    float* __restrict__ agg)
{
  __shared__ __align__(16) u16 SH[64 * 264];  // A view stride 168 (160 cols); M view 136; f32 view 132
  __shared__ int dstL[64];
  float* SHf = (float*)SH;

  const int t = threadIdx.x;
  const int wv = t >> 6, ln = t & 63;
  const int l15 = ln & 15, hi = ln >> 4;
  const int col0 = wv * 32;

  bf16x8 w1f[5][2], w2f[4][2];
#pragma unroll
  for (int kb = 0; kb < 5; ++kb)
#pragma unroll
    for (int nb = 0; nb < 2; ++nb)
      w1f[kb][nb] = *(const bf16x8*)(W1sT + (col0 + nb * 16 + l15) * 160 + kb * 32 + hi * 8);
#pragma unroll
  for (int kb = 0; kb < 4; ++kb)
#pragma unroll
    for (int nb = 0; nb < 2; ++nb)
      w2f[kb][nb] = *(const bf16x8*)(W2T + (col0 + nb * 16 + l15) * 128 + kb * 32 + hi * 8);
  float b1v[2], b2v[2];
#pragma unroll
  for (int nb = 0; nb < 2; ++nb) {
    b1v[nb] = b1[col0 + nb * 16 + l15];
    b2v[nb] = b2[col0 + nb * 16 + l15];
  }

  const int r = t >> 2, p = t & 3;
  const int NT = NE / 64;

  int tile = blockIdx.x;
  int s_nx = srcS[tile * 64 + r];
  int d_nx = dstS[tile * 64 + r];

  for (; tile < NT; tile += gridDim.x) {
    f32x4 acc1[4][2];
    // ---- gather: A row = [h[src](128) | ea(16) | 0(16)] ; acc1 <- Q[dst] ----
    {
      int e = tile * 64 + r;
      int s = s_nx;
      if (p == 0) dstL[r] = d_nx;
      const uint4* hs = (const uint4*)(h_bf + (size_t)s * 128) + p * 4;
      uint4* a1 = (uint4*)(&SH[r * 168]) + p * 4;
#pragma unroll
      for (int i = 0; i < 4; ++i) a1[i] = hs[i];
      if (p == 1) {
        const uint4* ea = (const uint4*)(eaS + (size_t)e * 16);
        uint4* aE = (uint4*)(&SH[r * 168 + 128]);
        aE[0] = ea[0]; aE[1] = ea[1];
      } else if (p == 2) {
        uint4 z = make_uint4(0, 0, 0, 0);
        uint4* aZ = (uint4*)(&SH[r * 168 + 144]);
        aZ[0] = z; aZ[1] = z;
      }
      // Q[dst] loads into acc1 (per-lane; dst runs make these L1/L2-hot)
      int e0 = tile * 64;
#pragma unroll
      for (int rb = 0; rb < 4; ++rb) {
#pragma unroll
        for (int i = 0; i < 4; ++i) {
          int dr = dstS[e0 + rb * 16 + hi * 4 + i];
          const float* qp = Q + (size_t)dr * 128 + col0 + l15;
          acc1[rb][0][i] = qp[0];
          acc1[rb][1][i] = qp[16];
        }
      }
      // prefetch next tile's indices (lands during compute)
      int tn = tile + gridDim.x;
      if (tn < NT) {
        int en = tn * 64 + r;
        s_nx = srcS[en];
        d_nx = dstS[en];
      }
    }
    __syncthreads();

    // ---- stage 1: acc1 += [64,160] @ [160,128] (continuation of Q chain) ----
#pragma unroll
    for (int kb = 0; kb < 5; ++kb) {
      bf16x8 af[4];
#pragma unroll
      for (int rb = 0; rb < 4; ++rb)
        af[rb] = *(const bf16x8*)(&SH[(rb * 16 + l15) * 168 + kb * 32 + hi * 8]);
#pragma unroll
      for (int rb = 0; rb < 4; ++rb)
#pragma unroll
        for (int nb = 0; nb < 2; ++nb)
          acc1[rb][nb] = __builtin_amdgcn_mfma_f32_16x16x32_bf16(af[rb], w1f[kb][nb], acc1[rb][nb], 0, 0, 0);
    }
    __syncthreads();  // A reads done before M overwrites union buffer

    // ---- write M (relu, bf16), stride 136 ----
#pragma unroll
    for (int rb = 0; rb < 4; ++rb)
#pragma unroll
      for (int nb = 0; nb < 2; ++nb)
#pragma unroll
        for (int i = 0; i < 4; ++i) {
          float v = acc1[rb][nb][i] + b1v[nb];
          SH[(rb * 16 + hi * 4 + i) * 136 + col0 + nb * 16 + l15] = f2bf(relu_f(v));
        }
    __syncthreads();

    // ---- stage 2: [64,128] @ [128,128] ----
    f32x4 acc2[4][2];
#pragma unroll
    for (int rb = 0; rb < 4; ++rb)
#pragma unroll
      for (int nb = 0; nb < 2; ++nb) acc2[rb][nb] = (f32x4){0.f, 0.f, 0.f, 0.f};
#pragma unroll
    for (int kb = 0; kb < 4; ++kb) {
      bf16x8 af[4];
#pragma unroll
      for (int rb = 0; rb < 4; ++rb)
        af[rb] = *(const bf16x8*)(&SH[(rb * 16 + l15) * 136 + kb * 32 + hi * 8]);
#pragma unroll
      for (int rb = 0; rb < 4; ++rb)
#pragma unroll
        for (int nb = 0; nb < 2; ++nb)
          acc2[rb][nb] = __builtin_amdgcn_mfma_f32_16x16x32_bf16(af[rb], w2f[kb][nb], acc2[rb][nb], 0, 0, 0);
    }
    __syncthreads();  // M reads done before f32 view overwrites union buffer

    // ---- write m (relu, f32) to SHf [64][132] ----
#pragma unroll
    for (int rb = 0; rb < 4; ++rb)
#pragma unroll
      for (int nb = 0; nb < 2; ++nb)
#pragma unroll
        for (int i = 0; i < 4; ++i) {
          float v = relu_f(acc2[rb][nb][i] + b2v[nb]);
          SHf[(rb * 16 + hi * 4 + i) * 132 + col0 + nb * 16 + l15] = v;
        }
    __syncthreads();

    // ---- segmented scan over sorted dst runs; one atomic per (segment, col) ----
    {
      int c = t & 127, hh = t >> 7;
      int r0 = hh * 32;
      int d0 = dstL[r0];
      float run = SHf[r0 * 132 + c];
#pragma unroll 4
      for (int rr = r0 + 1; rr < r0 + 32; ++rr) {
        int d = dstL[rr];              // wave-uniform
        float v = SHf[rr * 132 + c];
        if (d != d0) {                 // wave-uniform branch
          atomicAdd(&agg[(size_t)d0 * 128 + c], run);
          d0 = d; run = v;
        } else {
          run += v;
        }
      }
      atomicAdd(&agg[(size_t)d0 * 128 + c], run);
    }
    __syncthreads();  // scan reads done before next iteration's LDS writes
  }
}

// ============================ node update (+ fused Q for next layer) ==========================
// u = relu(cat(h,agg) @ W1 + b1) @ W2 + b2;  h += u  (h_bf mirrored)
// if W1dN != null: Q = new_h_bf @ W1dN (bit-identical to standalone chain)
__global__ __launch_bounds__(256, 4) void k_node_update(
    const float* __restrict__ aggIn,
    const u16* __restrict__ W1T, const float* __restrict__ b1,
    const u16* __restrict__ W2T, const float* __restrict__ b2,
    const u16* __restrict__ W1dN, float* __restrict__ Q,
    float* __restrict__ h, u16* __restrict__ h_bf)
{
  __shared__ __align__(16) u16 SH[64 * 264];
  const int t = threadIdx.x;
  const int wv = t >> 6, ln = t & 63;
  const int l15 = ln & 15, hi = ln >> 4;
  const int col0 = wv * 32;

  bf16x8 w1f[8][2], w2f[4][2];
#pragma unroll
  for (int kb = 0; kb < 8; ++kb)
#pragma unroll
    for (int nb = 0; nb < 2; ++nb)
      w1f[kb][nb] = *(const bf16x8*)(W1T + (col0 + nb * 16 + l15) * 256 + kb * 32 + hi * 8);
#pragma unroll
  for (int kb = 0; kb < 4; ++kb)
#pragma unroll
    for (int nb = 0; nb < 2; ++nb)
      w2f[kb][nb] = *(const bf16x8*)(W2T + (col0 + nb * 16 + l15) * 128 + kb * 32 + hi * 8);
  float b1v[2], b2v[2];
#pragma unroll
  for (int nb = 0; nb < 2; ++nb) {
    b1v[nb] = b1[col0 + nb * 16 + l15];
    b2v[nb] = b2[col0 + nb * 16 + l15];
  }

  const int r = t >> 2, p = t & 3;
  const int tile = blockIdx.x;
  {
    int node = tile * 64 + r;
    if (node < NN) {
      const uint4* hv = (const uint4*)(h_bf + (size_t)node * 128) + p * 4;
      uint4* a0 = (uint4*)(&SH[r * 264]) + p * 4;
#pragma unroll
      for (int i = 0; i < 4; ++i) a0[i] = hv[i];
      const float4* ag = (const float4*)(aggIn + (size_t)node * 128) + p * 8;
#pragma unroll
      for (int i = 0; i < 4; ++i) {
        float4 v0 = ag[2 * i], v1 = ag[2 * i + 1];
        u16x8 o;
        o[0] = f2bf(v0.x); o[1] = f2bf(v0.y); o[2] = f2bf(v0.z); o[3] = f2bf(v0.w);
        o[4] = f2bf(v1.x); o[5] = f2bf(v1.y); o[6] = f2bf(v1.z); o[7] = f2bf(v1.w);
        *(u16x8*)(&SH[r * 264 + 128 + p * 32 + i * 8]) = o;
      }
    }
  }
  __syncthreads();

  f32x4 acc1[4][2];
#pragma unroll
  for (int rb = 0; rb < 4; ++rb)
#pragma unroll
    for (int nb = 0; nb < 2; ++nb) acc1[rb][nb] = (f32x4){0.f, 0.f, 0.f, 0.f};
#pragma unroll
  for (int kb = 0; kb < 8; ++kb) {
    bf16x8 af[4];
#pragma unroll
    for (int rb = 0; rb < 4; ++rb)
      af[rb] = *(const bf16x8*)(&SH[(rb * 16 + l15) * 264 + kb * 32 + hi * 8]);
#pragma unroll
    for (int rb = 0; rb < 4; ++rb)
#pragma unroll
      for (int nb = 0; nb < 2; ++nb)
        acc1[rb][nb] = __builtin_amdgcn_mfma_f32_16x16x32_bf16(af[rb], w1f[kb][nb], acc1[rb][nb], 0, 0, 0);
  }
  __syncthreads();

#pragma unroll
  for (int rb = 0; rb < 4; ++rb)
#pragma unroll
    for (int nb = 0; nb < 2; ++nb)
#pragma unroll
      for (int i = 0; i < 4; ++i) {
        float v = acc1[rb][nb][i] + b1v[nb];
        SH[(rb * 16 + hi * 4 + i) * 136 + col0 + nb * 16 + l15] = f2bf(relu_f(v));
      }
  __syncthreads();

  f32x4 acc2[4][2];
#pragma unroll
  for (int rb = 0; rb < 4; ++rb)
#pragma unroll
    for (int nb = 0; nb < 2; ++nb) acc2[rb][nb] = (f32x4){0.f, 0.f, 0.f, 0.f};
#pragma unroll
  for (int kb = 0; kb < 4; ++kb) {
    bf16x8 af[4];
#pragma unroll
    for (int rb = 0; rb < 4; ++rb)
      af[rb] = *(const bf16x8*)(&SH[(rb * 16 + l15) * 136 + kb * 32 + hi * 8]);
#pragma unroll
    for (int rb = 0; rb < 4; ++rb)
#pragma unroll
      for (int nb = 0; nb < 2; ++nb)
        acc2[rb][nb] = __builtin_amdgcn_mfma_f32_16x16x32_bf16(af[rb], w2f[kb][nb], acc2[rb][nb], 0, 0, 0);
  }
  __syncthreads();  // all stage-2 LDS reads done before the new-h image overwrites

#pragma unroll
  for (int rb = 0; rb < 4; ++rb)
#pragma unroll
    for (int nb = 0; nb < 2; ++nb)
#pragma unroll
      for (int i = 0; i < 4; ++i) {
        int row = rb * 16 + hi * 4 + i;
        int node = tile * 64 + row;
        if (node < NN) {
          int col = col0 + nb * 16 + l15;
          float v = acc2[rb][nb][i] + b2v[nb];
          size_t ix = (size_t)node * 128 + col;
          float nh = h[ix] + v;
          u16 hb = f2bf(nh);
          h[ix] = nh;
          h_bf[ix] = hb;
          if (W1dN) SH[row * 136 + col] = hb;   // stage new h (bf16) for fused Q
        }
      }

  // ---- fused Q = new_h_bf @ W1dN (next layer); bit-identical to standalone chain ----
  if (W1dN) {
    __syncthreads();
    bf16x8 wq[4][2];
#pragma unroll
    for (int kb = 0; kb < 4; ++kb)
#pragma unroll
      for (int nb = 0; nb < 2; ++nb)
        wq[kb][nb] = *(const bf16x8*)(W1dN + (col0 + nb * 16 + l15) * 128 + kb * 32 + hi * 8);
    f32x4 aq[4][2];
#pragma unroll
    for (int rb = 0; rb < 4; ++rb)
#pragma unroll
      for (int nb = 0; nb < 2; ++nb) aq[rb][nb] = (f32x4){0.f, 0.f, 0.f, 0.f};
#pragma unroll
    for (int kb = 0; kb < 4; ++kb) {
      bf16x8 af[4];
#pragma unroll
      for (int rb = 0; rb < 4; ++rb)
        af[rb] = *(const bf16x8*)(&SH[(rb * 16 + l15) * 136 + kb * 32 + hi * 8]);
#pragma unroll
      for (int rb = 0; rb < 4; ++rb)
#pragma unroll
        for (int nb = 0; nb < 2; ++nb)
          aq[rb][nb] = __builtin_amdgcn_mfma_f32_16x16x32_bf16(af[rb], wq[kb][nb], aq[rb][nb], 0, 0, 0);
    }
#pragma unroll
    for (int rb = 0; rb < 4; ++rb)
#pragma unroll
      for (int nb = 0; nb < 2; ++nb)
#pragma unroll
        for (int i = 0; i < 4; ++i) {
          int row = rb * 16 + hi * 4 + i;
          int node = tile * 64 + row;
          if (node < NN)
            Q[(size_t)node * 128 + col0 + nb * 16 + l15] = aq[rb][nb][i];
        }
  }
}

// ============================ pre-pool MLP + global add pool (segmented, batch sorted) =========
__global__ __launch_bounds__(256, 4) void k_prepool(
    const u16* __restrict__ h_bf, const int* __restrict__ batch,
    const u16* __restrict__ W1T, const float* __restrict__ b1,
    const u16* __restrict__ W2T, const float* __restrict__ b2,
    float* __restrict__ g)
{
  __shared__ __align__(16) u16 SH[64 * 272];  // A [64][136] @0; M [64][136] @64*136; f32 view [64][132]
  __shared__ int bL[64];
  float* SHf = (float*)SH;
  const int t = threadIdx.x;
  const int wv = t >> 6, ln = t & 63;
  const int l15 = ln & 15, hi = ln >> 4;
  const int col0 = wv * 32;

  bf16x8 w1f[4][2], w2f[4][2];
#pragma unroll
  for (int kb = 0; kb < 4; ++kb)
#pragma unroll
    for (int nb = 0; nb < 2; ++nb) {
      w1f[kb][nb] = *(const bf16x8*)(W1T + (col0 + nb * 16 + l15) * 128 + kb * 32 + hi * 8);
      w2f[kb][nb] = *(const bf16x8*)(W2T + (col0 + nb * 16 + l15) * 128 + kb * 32 + hi * 8);
    }
  float b1v[2], b2v[2];
#pragma unroll
  for (int nb = 0; nb < 2; ++nb) {
    b1v[nb] = b1[col0 + nb * 16 + l15];
    b2v[nb] = b2[col0 + nb * 16 + l15];
  }

  const int r = t >> 2, p = t & 3;
  const int tile = blockIdx.x;
  {
    int node = tile * 64 + r;
    int nclamp = node < NN ? node : NN - 1;
    if (p == 0) bL[r] = batch[nclamp];
    if (node < NN) {
      const uint4* hv = (const uint4*)(h_bf + (size_t)node * 128) + p * 4;
      uint4* a0 = (uint4*)(&SH[r * 136]) + p * 4;
#pragma unroll
      for (int i = 0; i < 4; ++i) a0[i] = hv[i];
    }
  }
  __syncthreads();

  f32x4 acc1[4][2];
#pragma unroll
  for (int rb = 0; rb < 4; ++rb)
#pragma unroll
    for (int nb = 0; nb < 2; ++nb) acc1[rb][nb] = (f32x4){0.f, 0.f, 0.f, 0.f};
#pragma unroll
  for (int kb = 0; kb < 4; ++kb) {
    bf16x8 af[4];
#pragma unroll
    for (int rb = 0; rb < 4; ++rb)
      af[rb] = *(const bf16x8*)(&SH[(rb * 16 + l15) * 136 + kb * 32 + hi * 8]);
#pragma unroll
    for (int rb = 0; rb < 4; ++rb)
#pragma unroll
      for (int nb = 0; nb < 2; ++nb)
        acc1[rb][nb] = __builtin_amdgcn_mfma_f32_16x16x32_bf16(af[rb], w1f[kb][nb], acc1[rb][nb], 0, 0, 0);
  }
  // M region disjoint from A region: no barrier needed before write
#pragma unroll
  for (int rb = 0; rb < 4; ++rb)
#pragma unroll
    for (int nb = 0; nb < 2; ++nb)
#pragma unroll
      for (int i = 0; i < 4; ++i) {
        float v = acc1[rb][nb][i] + b1v[nb];
        SH[64 * 136 + (rb * 16 + hi * 4 + i) * 136 + col0 + nb * 16 + l15] = f2bf(relu_f(v));
      }
  __syncthreads();

  f32x4 acc2[4][2];
#pragma unroll
  for (int rb = 0; rb < 4; ++rb)
#pragma unroll
    for (int nb = 0; nb < 2; ++nb) acc2[rb][nb] = (f32x4){0.f, 0.f, 0.f, 0.f};
#pragma unroll
  for (int kb = 0; kb < 4; ++kb) {
    bf16x8 af[4];
#pragma unroll
    for (int rb = 0; rb < 4; ++rb)
      af[rb] = *(const bf16x8*)(&SH[64 * 136 + (rb * 16 + l15) * 136 + kb * 32 + hi * 8]);
#pragma unroll
    for (int rb = 0; rb < 4; ++rb)
#pragma unroll
      for (int nb = 0; nb < 2; ++nb)
        acc2[rb][nb] = __builtin_amdgcn_mfma_f32_16x16x32_bf16(af[rb], w2f[kb][nb], acc2[rb][nb], 0, 0, 0);
  }
  __syncthreads();  // all A/M reads done before f32 view overwrites

  // write p (f32, zero for invalid rows) to SHf [64][132]
#pragma unroll
  for (int rb = 0; rb < 4; ++rb)
#pragma unroll
    for (int nb = 0; nb < 2; ++nb)
#pragma unroll
      for (int i = 0; i < 4; ++i) {
        int row = rb * 16 + hi * 4 + i;
        int node = tile * 64 + row;
        float v = acc2[rb][nb][i] + b2v[nb];
        SHf[row * 132 + col0 + nb * 16 + l15] = (node < NN) ? v : 0.f;
      }
  __syncthreads();

  // segmented scan over sorted batch ids; one atomic per (segment, col)
  {
    int c = t & 127, hh = t >> 7;
    int r0 = hh * 32;
    int b0 = bL[r0];
    float run = SHf[r0 * 132 + c];
#pragma unroll 4
    for (int rr = r0 + 1; rr < r0 + 32; ++rr) {
      int b = bL[rr];                // wave-uniform
      float v = SHf[rr * 132 + c];
      if (b != b0) {                 // wave-uniform branch
        atomicAdd(&g[(size_t)b0 * 128 + c], run);
        b0 = b; run = v;
      } else {
        run += v;
      }
    }
    atomicAdd(&g[(size_t)b0 * 128 + c], run);
  }
}

// ============================ post-pool MLP (tiny, fp32) ============================
__global__ void k_postpool(const float* __restrict__ g,
                           const float* __restrict__ W1, const float* __restrict__ b1,
                           const float* __restrict__ W2, const float* __restrict__ b2,
                           float* __restrict__ out)
{
  __shared__ float gl[16][128];
  __shared__ float t1[16][129];
  int t = threadIdx.x;
  for (int i = t; i < 16 * 128; i += 256) gl[i >> 7][i & 127] = g[i];
  __syncthreads();
  for (int o = t; o < 16 * 128; o += 256) {
    int r = o >> 7, c = o & 127;
    float s = b1[c];
    for (int k = 0; k < 128; ++k) s += gl[r][k] * W1[k * 128 + c];
    t1[r][c] = relu_f(s);
  }
  __syncthreads();
  for (int o = t; o < 16 * 128; o += 256) {
    int r = o >> 7, c = o & 127;
    float s = b2[c];
    for (int k = 0; k < 128; ++k) s += t1[r][k] * W2[k * 128 + c];
    out[o] = s;
  }
}

// ============================ host ============================
extern "C" void kernel_launch(void* const* d_in, const int* in_sizes, int n_in,
                              void* d_out, int out_size, void* d_ws, size_t ws_size,
                              hipStream_t stream) {
  (void)in_sizes; (void)n_in; (void)out_size; (void)ws_size;
  const float* x      = (const float*)d_in[0];
  const int*   ei     = (const int*)d_in[1];
  const float* ea     = (const float*)d_in[2];
  const int*   batch  = (const int*)d_in[3];
  const float* embW   = (const float*)d_in[4];
  const float* embb   = (const float*)d_in[5];
  const float* msgW1  = (const float*)d_in[6];
  const float* msgb1  = (const float*)d_in[7];
  const float* msgW2  = (const float*)d_in[8];
  const float* msgb2  = (const float*)d_in[9];
  const float* updW1  = (const float*)d_in[10];
  const float* updb1  = (const float*)d_in[11];
  const float* updW2  = (const float*)d_in[12];
  const float* updb2  = (const float*)d_in[13];
  const float* preW1  = (const float*)d_in[14];
  const float* preb1  = (const float*)d_in[15];
  const float* preW2  = (const float*)d_in[16];
  const float* preb2  = (const float*)d_in[17];
  const float* postW1 = (const float*)d_in[18];
  const float* postb1 = (const float*)d_in[19];
  const float* postW2 = (const float*)d_in[20];
  const float* postb2 = (const float*)d_in[21];

  const int* srcI = ei;
  const int* dstI = ei + NE;

  char* ws = (char*)d_ws;
  size_t off = 0;
  auto alloc = [&](size_t bytes) -> void* {
    void* pp = ws + off;
    off += (bytes + 255) & ~(size_t)255;
    return pp;
  };
  float* h      = (float*)alloc((size_t)NN * 128 * 4);
  float* agg    = (float*)alloc((size_t)NN * 128 * 4);
  float* Q      = (float*)alloc((size_t)NN * 128 * 4);
  float* g      = (float*)alloc(16 * 128 * 4);
  u16*   h_bf   = (u16*)alloc((size_t)NN * 128 * 2);
  u16*   eaS    = (u16*)alloc((size_t)NE * 16 * 2);
  int*   counts = (int*)alloc((size_t)NN * 4);
  int*   cur    = (int*)alloc((size_t)NN * 4);
  int*   eperm  = (int*)alloc((size_t)NE * 4);
  int*   srcS   = (int*)alloc((size_t)NE * 4);
  int*   dstS   = (int*)alloc((size_t)NE * 4);
  u16*   embWT  = (u16*)alloc(128 * 128 * 2);
  u16*   msgW1dT = (u16*)alloc(4 * 128 * 128 * 2);
  u16*   msgW1sT = (u16*)alloc(4 * 128 * 160 * 2);
  u16*   msgW2T = (u16*)alloc(4 * 128 * 128 * 2);
  u16*   updW1T = (u16*)alloc(4 * 128 * 256 * 2);
  u16*   updW2T = (u16*)alloc(4 * 128 * 128 * 2);
  u16*   preW1T = (u16*)alloc(128 * 128 * 2);
  u16*   preW2T = (u16*)alloc(128 * 128 * 2);

  // ---- CSR build (dst-sorted edge order) ----
  hipMemsetAsync(counts, 0, (size_t)NN * 4, stream);
  const int eBlocks = (NE + 255) / 256;
  k_hist<<<eBlocks, 256, 0, stream>>>(dstI, counts);
  k_scan<<<1, 1024, 0, stream>>>(counts, cur);
  k_scatter<<<eBlocks, 256, 0, stream>>>(dstI, cur, eperm);
  k_permute<<<eBlocks, 256, 0, stream>>>(eperm, srcI, dstI, ea, srcS, dstS, eaS);

  // ---- weight pack ----
  {
    PackArgs pa;
    int di = 0;
    auto add = [&](const float* s, u16* dp, int K, int Kpad) {
      pa.src[di] = s; pa.dst[di] = dp; pa.K[di] = K; pa.Kpad[di] = Kpad; ++di;
    };
    add(embW, embWT, 128, 128);
    for (int l = 0; l < 4; ++l) add(msgW1 + (size_t)l * 272 * 128, msgW1dT + (size_t)l * 128 * 128, 128, 128);
    for (int l = 0; l < 4; ++l) add(msgW1 + (size_t)l * 272 * 128 + 128 * 128, msgW1sT + (size_t)l * 128 * 160, 144, 160);
    for (int l = 0; l < 4; ++l) add(msgW2 + (size_t)l * 128 * 128, msgW2T + (size_t)l * 128 * 128, 128, 128);
    for (int l = 0; l < 4; ++l) add(updW1 + (size_t)l * 256 * 128, updW1T + (size_t)l * 128 * 256, 256, 256);
    for (int l = 0; l < 4; ++l) add(updW2 + (size_t)l * 128 * 128, updW2T + (size_t)l * 128 * 128, 128, 128);
    add(preW1, preW1T, 128, 128);
    add(preW2, preW2T, 128, 128);
    k_pack_all<<<23 * 144, 256, 0, stream>>>(pa);
  }

  const int nodeTiles = (NN + 63) / 64;
  // embed + fused Q for layer 0
  k_embed<<<nodeTiles, 256, 0, stream>>>(x, embWT, embb, msgW1dT, Q, h, h_bf);

  for (int l = 0; l < 4; ++l) {
    hipMemsetAsync(agg, 0, (size_t)NN * 128 * 4, stream);
    k_edge<<<1024, 256, 0, stream>>>(srcS, dstS, h_bf, eaS, Q,
                                     msgW1sT + (size_t)l * 128 * 160, msgb1 + l * 128,
                                     msgW2T + (size_t)l * 128 * 128, msgb2 + l * 128, agg);
    const u16* w1dNext = (l < 3) ? (msgW1dT + (size_t)(l + 1) * 128 * 128) : (const u16*)nullptr;
    k_node_update<<<nodeTiles, 256, 0, stream>>>(agg,
                                    updW1T + (size_t)l * 128 * 256, updb1 + l * 128,
                                    updW2T + (size_t)l * 128 * 128, updb2 + l * 128,
                                    w1dNext, Q, h, h_bf);
  }

  hipMemsetAsync(g, 0, 16 * 128 * 4, stream);
  k_prepool<<<nodeTiles, 256, 0, stream>>>(h_bf, batch, preW1T, preb1, preW2T, preb2, g);
  k_postpool<<<1, 256, 0, stream>>>(g, postW1, postb1, postW2, postb2, (float*)d_out);
}